// Round 11
// baseline (386.507 us; speedup 1.0000x reference)
//
#include <hip/hip_runtime.h>
#include <hip/hip_bf16.h>
#include <cstdint>
#include <cstddef>

#define BB 2
#define SS 2048
#define DD 1024
#define HH 16
#define HDIM 64
#define FF 4096
#define RR (BB*SS)   // 4096 rows total

typedef __attribute__((ext_vector_type(8))) short short8;
typedef __attribute__((ext_vector_type(4))) float floatx4;

__device__ __forceinline__ unsigned short f2bf(float f){
    __hip_bfloat16 h = __float2bfloat16(f);
    return *reinterpret_cast<unsigned short*>(&h);
}

__device__ __forceinline__ void load_lds16(const void* g, void* l){
    __builtin_amdgcn_global_load_lds((__attribute__((address_space(1))) void*)g,
                                     (__attribute__((address_space(3))) void*)l, 16, 0, 0);
}

// LDS tile layout (64-wide bf16 rows): element chunk c (8 elems) of row r lives at
// chunk (c ^ (r&7)). Staging swizzles the global SOURCE column; readers XOR the
// chunk index with (row&7). Measured: SQ_LDS_BANK_CONFLICT == 0 with this.

// ---------------- GEMM: C[M,N] = A[M,K] * B[N,K]^T (bf16 in) ----------------
// FINAL CONFIG for 128-tile GEMMs (= R6/R10, measured-best; R10 total 358.2us).
// Ledger: single-buffer (256,3) BEST | dbuf worse | 3-buf vmcnt neutral | BM=256 -5us
// | min-waves pin -7us. Mechanism: stage -> barrier -> compute -> barrier; cross-block
// overlap (m114) at 3+ blocks/CU supplies the pipelining.
// EPI: 1 = QKV split-scatter, 2 = +residual -> fp32, 3 = GELU(sigmoid) -> bf16,
//      4 = fp32 partial store to cf + z*M*N
template<int BM, int BN, int EPI>
__global__ __launch_bounds__(256, 3)
void gemm_bt(const unsigned short* __restrict__ A,
             const unsigned short* __restrict__ B,
             int M, int N, int K, int KS,
             float* __restrict__ cf,
             const float* __restrict__ resid,
             unsigned short* __restrict__ cbf,
             unsigned short* __restrict__ qb,
             float* __restrict__ kout,
             unsigned short* __restrict__ kbf,
             float* __restrict__ vout)
{
    constexpr int MI_M = (BN==128) ? (BM/32) : (BM/64);   // per-wave 16-row tiles
    __shared__ __align__(16) unsigned short As[BM*64];
    __shared__ __align__(16) unsigned short Bs[BN*64];
    const int tid  = threadIdx.x;
    const int lane = tid & 63;
    const int wave = tid >> 6;
    const int quad = lane >> 4, l15 = lane & 15;
    const int wrow = (BN==128) ? (wave>>1)*(BM/2) : wave*(BM/4);
    const int wcol = (BN==128) ? (wave&1)*64 : 0;

    // T1 XCD swizzle: bid%8 = this block's XCD; give each XCD a contiguous run.
    const unsigned gx = gridDim.x;
    const unsigned nwg = gx * gridDim.y;
    const unsigned bid = blockIdx.y * gx + blockIdx.x;
    const unsigned cpx = nwg >> 3;
    const unsigned swz = (bid & 7) * cpx + (bid >> 3);
    const int bx = (int)(swz % gx), by = (int)(swz / gx);

    const int gm0 = by * BM, gn0 = bx * BN;
    const int k0 = blockIdx.z * KS;
    const int niter = KS >> 6;
    const int phase = (int)((unsigned)(bx + by) % (unsigned)niter);

    floatx4 acc[MI_M][4];
#pragma unroll
    for (int i=0;i<MI_M;i++)
#pragma unroll
        for (int j=0;j<4;j++) acc[i][j] = (floatx4){0.f,0.f,0.f,0.f};

    const int rsub = lane >> 3;                    // row within 8-row chunk (= row&7)
    const int d8   = (lane & 7) * 8;               // LDS dest offset within row
    const int ksub = ((lane & 7) ^ rsub) * 8;      // swizzled global source k-offset
    constexpr int nchw = (BM + BN) / 32;           // staging chunks per wave

    auto stage = [&](int kt){
#pragma unroll
        for (int i=0;i<nchw;i++){
            int c = wave*nchw + i;   // wave-uniform chunk id
            if (c < BM/8)
                load_lds16(A + (size_t)(gm0 + c*8 + rsub)*K + kt + ksub,
                           &As[c*512 + rsub*64 + d8]);
            else
                load_lds16(B + (size_t)(gn0 + (c-BM/8)*8 + rsub)*K + kt + ksub,
                           &Bs[(c-BM/8)*512 + rsub*64 + d8]);
        }
    };

    auto compute = [&](){
#pragma unroll
        for (int kk=0; kk<64; kk+=32){
            const int cb4 = kk >> 3;   // 0 or 4
            short8 af[MI_M], bfr[4];
#pragma unroll
            for (int mi=0;mi<MI_M;mi++){
                int row = wrow + mi*16 + l15;
                af[mi] = *(const short8*)&As[row*64 + (((cb4+quad) ^ (row&7)))*8];
            }
#pragma unroll
            for (int ni=0;ni<4;ni++){
                int row = wcol + ni*16 + l15;
                bfr[ni] = *(const short8*)&Bs[row*64 + (((cb4+quad) ^ (row&7)))*8];
            }
#pragma unroll
            for (int mi=0;mi<MI_M;mi++)
#pragma unroll
                for (int ni=0;ni<4;ni++)
                    acc[mi][ni] = __builtin_amdgcn_mfma_f32_16x16x32_bf16(af[mi], bfr[ni], acc[mi][ni], 0, 0, 0);
        }
    };

    for (int it=0; it<niter; it++){
        int j = it + phase; if (j >= niter) j -= niter;
        stage(k0 + j*64);
        __syncthreads();   // vmcnt(0)+lgkmcnt(0) drain: tile present for all waves
        compute();
        __syncthreads();   // all waves' ds_reads done before next stage overwrites
    }

#pragma unroll
    for (int mi=0;mi<MI_M;mi++)
#pragma unroll
        for (int ni=0;ni<4;ni++)
#pragma unroll
            for (int r=0;r<4;r++){
                int row = gm0 + wrow + mi*16 + quad*4 + r;
                int col = gn0 + wcol + ni*16 + l15;
                float v = acc[mi][ni][r];
                if constexpr (EPI == 1){
                    // QKV split: region is tile-uniform (gn0 aligned to 128 < 1024)
                    int region = gn0 >> 10;
                    if (region == 0){
                        qb[(size_t)row*1024 + col] = f2bf(v);
                    } else {
                        int c1 = col & 1023;
                        int h = c1 >> 6, d = c1 & 63;
                        int b = row >> 11, s = row & (SS-1);
                        size_t o = ((size_t)((b*HH + h)*SS + s))*HDIM + d;
                        if (region == 1){ kout[o] = v; kbf[o] = f2bf(v); }
                        else            { vout[o] = v; }
                    }
                } else if constexpr (EPI == 2){
                    size_t o = (size_t)row*N + col;
                    cf[o] = v + resid[o];
                } else if constexpr (EPI == 3){
                    // tanh-GELU via sigmoid identity: 0.5(1+tanh(u)) = 1/(1+e^-2u)
                    float u = v*(0.79788456f + 0.0356774081f*v*v);
                    float g = v / (1.f + exp2f(-2.88539008f*u));
                    cbf[(size_t)row*N + col] = f2bf(g);
                } else {   // EPI == 4: split-K fp32 partial
                    cf[(size_t)blockIdx.z*M*N + (size_t)row*N + col] = v;
                }
            }
}

// ---------------- R11: 256x256-tile, 8-wave, counted-vmcnt 2-deep pipeline ---------
// FFN1 only (M=N=4096 -> grid 16x16 = 256 blocks = exactly 1/CU at 128 KB LDS).
// T3/T4-style: prologue stages K-tiles 0,1 (8 loads/wave each). Iter t:
//   vmcnt(8)  -> tile t's own 8 loads done; tile t+1's 8 stay IN FLIGHT across
//                both barriers (the counted-wait mechanism __syncthreads forbids)
//   s_barrier -> every wave passed its own vmcnt(8), so ALL tile-t staging visible
//   compute tile t (B-frags once, then 4 m-quadrants x 16 MFMA; compiler lgkmcnts)
//   s_barrier -> all waves' ds_reads of buf retired (they feed MFMAs before barrier)
//   stage tile t+2 into buf (WAR-safe: ordered after barrier-2)
// Last iter waits vmcnt(0) (nothing staged beyond). Barriers exec-uniform. Memory-
// clobber asm fences pin LDS accesses between the raw barriers. Reuses the session's
// measured conflict-free XOR-swizzle addressing verbatim.
__global__ __launch_bounds__(512, 2) void gemm256_gelu(const unsigned short* __restrict__ A,
                                                       const unsigned short* __restrict__ B,
                                                       int K, int N,
                                                       unsigned short* __restrict__ cbf)
{
    __shared__ __align__(16) unsigned short As[2][256*64];   // 64 KB
    __shared__ __align__(16) unsigned short Bs[2][256*64];   // 64 KB
    const int tid  = threadIdx.x;
    const int lane = tid & 63;
    const int wave = tid >> 6;          // 0..7
    const int wm   = wave >> 2;         // 0..1  (M half)
    const int wn   = wave & 3;          // 0..3  (N quarter)
    const int quad = lane >> 4, l15 = lane & 15;

    // T1 XCD swizzle (nwg = 256, %8 == 0 -> bijective)
    const unsigned gx = gridDim.x;
    const unsigned nwg = gx * gridDim.y;
    const unsigned bid = blockIdx.y * gx + blockIdx.x;
    const unsigned cpx = nwg >> 3;
    const unsigned swzb = (bid & 7) * cpx + (bid >> 3);
    const int bx = (int)(swzb % gx), by = (int)(swzb / gx);
    const int gm0 = by * 256, gn0 = bx * 256;

    const int niter = K >> 6;                          // 16 for K=1024
    const int phase = (int)((unsigned)(bx + by) % (unsigned)niter);

    floatx4 acc[8][4];
#pragma unroll
    for (int i=0;i<8;i++)
#pragma unroll
        for (int j=0;j<4;j++) acc[i][j] = (floatx4){0.f,0.f,0.f,0.f};

    const int rsub = lane >> 3;
    const int d8   = (lane & 7) * 8;
    const int ksub = ((lane & 7) ^ rsub) * 8;

    // stage one full K-tile (A 256x64 + B 256x64): 64 chunks, 8 waves x 8 chunks,
    // 8 load-instructions per wave (this is what vmcnt counts).
    auto stage = [&](int kt, int buf){
#pragma unroll
        for (int i=0;i<8;i++){
            int c = wave*8 + i;
            if (c < 32)
                load_lds16(A + (size_t)(gm0 + c*8 + rsub)*K + kt + ksub,
                           &As[buf][c*512 + rsub*64 + d8]);
            else
                load_lds16(B + (size_t)(gn0 + (c-32)*8 + rsub)*K + kt + ksub,
                           &Bs[buf][(c-32)*512 + rsub*64 + d8]);
        }
    };

    auto jof = [&](int t){ int j = t + phase; if (j >= niter) j -= niter; return j; };

    stage(jof(0)*64, 0);
    if (niter > 1) stage(jof(1)*64, 1);

    for (int t=0; t<niter; t++){
        const int buf = t & 1;
        if (t+1 < niter) asm volatile("s_waitcnt vmcnt(8)" ::: "memory");
        else             asm volatile("s_waitcnt vmcnt(0)" ::: "memory");
        __builtin_amdgcn_s_barrier();
        asm volatile("" ::: "memory");
        const unsigned short* as = As[buf];
        const unsigned short* bs = Bs[buf];

        // B fragments once per K-tile (held across the 4 m-quadrants)
        short8 bfr[2][4];
#pragma unroll
        for (int kk=0;kk<2;kk++)
#pragma unroll
            for (int ni=0;ni<4;ni++){
                int row = wn*64 + ni*16 + l15;
                bfr[kk][ni] = *(const short8*)&bs[row*64 + (((kk*4+quad) ^ (row&7)))*8];
            }
        // 4 m-quadrants x (2 m-frags x 4 n-frags x 2 kk) = 64 MFMA / wave / K-tile
#pragma unroll
        for (int q=0;q<4;q++){
            short8 af[2][2];
#pragma unroll
            for (int kk=0;kk<2;kk++)
#pragma unroll
                for (int mi=0;mi<2;mi++){
                    int row = wm*128 + q*32 + mi*16 + l15;
                    af[kk][mi] = *(const short8*)&as[row*64 + (((kk*4+quad) ^ (row&7)))*8];
                }
#pragma unroll
            for (int kk=0;kk<2;kk++)
#pragma unroll
                for (int mi=0;mi<2;mi++)
#pragma unroll
                    for (int ni=0;ni<4;ni++)
                        acc[q*2+mi][ni] = __builtin_amdgcn_mfma_f32_16x16x32_bf16(
                            af[kk][mi], bfr[kk][ni], acc[q*2+mi][ni], 0, 0, 0);
        }
        asm volatile("" ::: "memory");
        __builtin_amdgcn_s_barrier();          // all waves done reading buf
        if (t+2 < niter) stage(jof(t+2)*64, buf);
    }

#pragma unroll
    for (int mf=0; mf<8; mf++)
#pragma unroll
        for (int ni=0;ni<4;ni++)
#pragma unroll
            for (int r=0;r<4;r++){
                int row = gm0 + wm*128 + mf*16 + quad*4 + r;
                int col = gn0 + wn*64 + ni*16 + l15;
                float v = acc[mf][ni][r];
                float u = v*(0.79788456f + 0.0356774081f*v*v);
                float g = v / (1.f + exp2f(-2.88539008f*u));
                cbf[(size_t)row*N + col] = f2bf(g);
            }
}

// ---------------- split-K combine: out = p0 + p1 + resid (float4) ----------------
__global__ __launch_bounds__(256) void combine2_kernel(const float* __restrict__ p0,
                                                       const float* __restrict__ p1,
                                                       const float* __restrict__ resid,
                                                       float* __restrict__ out, int n4)
{
    const int i = blockIdx.x*256 + threadIdx.x;
    if (i >= n4) return;
    float4 a = ((const float4*)p0)[i];
    float4 b = ((const float4*)p1)[i];
    float4 c = ((const float4*)resid)[i];
    ((float4*)out)[i] = make_float4(a.x+b.x+c.x, a.y+b.y+c.y, a.z+b.z+c.z, a.w+b.w+c.w);
}

// ---------------- flash attention: paired causal Q-tiles — FROZEN R0 body ----------
// Variant ledger: paired-R0 56.4 | setprio 59.0 | split-loop 60.0 | split-KV 62.9 |
// single-Q 75.6. Every restructure lost; do not modify.
__global__ __launch_bounds__(256) void attn_kernel(const unsigned short* __restrict__ qbf,
                                                   const unsigned short* __restrict__ kbf,
                                                   const unsigned short* __restrict__ vtbf,
                                                   unsigned short* __restrict__ ctx)
{
    __shared__ unsigned short Ks[2][64*64];   // 16 KB
    __shared__ unsigned short Vs[2][64*64];   // 16 KB
    __shared__ unsigned short Ps[4][16*64];   //  8 KB (per-wave P buffers)
    const int tid  = threadIdx.x;
    const int lane = tid & 63;
    const int wave = tid >> 6;
    const int quad = lane >> 4, l15 = lane & 15;
    const int aqt = blockIdx.x;            // 0..15
    const int bqt = 31 - aqt;              // 16..31
    const int bh = blockIdx.y;
    const int b = bh >> 4, h = bh & 15;
    const int q0a = aqt * 64, q0b = bqt * 64;

    const unsigned short* kb  = kbf  + (size_t)bh * SS * HDIM;
    const unsigned short* vtb = vtbf + (size_t)bh * HDIM * SS;

    const unsigned short* qra = qbf + (size_t)(b*SS + q0a + wave*16 + l15)*DD + h*HDIM + quad*8;
    const unsigned short* qrb = qbf + (size_t)(b*SS + q0b + wave*16 + l15)*DD + h*HDIM + quad*8;
    short8 qa0 = *(const short8*)qra;
    short8 qa1 = *(const short8*)(qra + 32);
    short8 qb0 = *(const short8*)qrb;
    short8 qb1 = *(const short8*)(qrb + 32);

    float lpA[4] = {0.f,0.f,0.f,0.f}, lpB[4] = {0.f,0.f,0.f,0.f};
    floatx4 accA[4], accB[4];
#pragma unroll
    for (int n=0;n<4;n++){ accA[n] = (floatx4){0.f,0.f,0.f,0.f}; accB[n] = (floatx4){0.f,0.f,0.f,0.f}; }

    const int r8 = lane >> 3;                    // staged row mod 8
    const int c8 = ((lane & 7) ^ r8) * 8;        // swizzled source offset
    const int d8 = (lane & 7) * 8;               // dest offset within row
    const int nkt = bqt + 1;
    const float SC = 0.125f * 1.44269504f;       // 1/sqrt(64) * log2(e)

#pragma unroll
    for (int p=0;p<2;p++){
        int row = p*32 + wave*8 + r8;
        load_lds16(kb  + (size_t)row*HDIM + c8,  &Ks[0][row*64 + d8]);
        load_lds16(vtb + (size_t)row*SS   + c8,  &Vs[0][row*64 + d8]);
    }

    unsigned short* pl = Ps[wave];
    int cur = 0;
    for (int kt=0; kt<nkt; kt++){
        __syncthreads();
        if (kt+1 < nkt){
            int nb = cur ^ 1;
#pragma unroll
            for (int p=0;p<2;p++){
                int row = p*32 + wave*8 + r8;
                load_lds16(kb  + (size_t)((kt+1)*64 + row)*HDIM + c8, &Ks[nb][row*64 + d8]);
                load_lds16(vtb + (size_t)row*SS + (size_t)(kt+1)*64 + c8, &Vs[nb][row*64 + d8]);
            }
        }
        const unsigned short* ks = Ks[cur];
        const unsigned short* vs = Vs[cur];

        short8 kf0[4], kf1[4];
#pragma unroll
        for (int j=0;j<4;j++){
            int row = j*16 + l15;
            kf0[j] = *(const short8*)&ks[row*64 + ((quad     ^ (row&7)))*8];
            kf1[j] = *(const short8*)&ks[row*64 + (((quad+4) ^ (row&7)))*8];
        }
        short8 vf0[4], vf1[4];
#pragma unroll
        for (int n=0;n<4;n++){
            int row = n*16 + l15;
            vf0[n] = *(const short8*)&vs[row*64 + ((quad     ^ (row&7)))*8];
            vf1[n] = *(const short8*)&vs[row*64 + (((quad+4) ^ (row&7)))*8];
        }

        // ---- phase B (Q-tile bqt): always active ----
        {
            floatx4 s[4];
#pragma unroll
            for (int j=0;j<4;j++){
                floatx4 zz = (floatx4){0.f,0.f,0.f,0.f};
                zz = __builtin_amdgcn_mfma_f32_16x16x32_bf16(qb0, kf0[j], zz, 0, 0, 0);
                zz = __builtin_amdgcn_mfma_f32_16x16x32_bf16(qb1, kf1[j], zz, 0, 0, 0);
                s[j] = zz;
            }
#pragma unroll
            for (int j=0;j<4;j++)
#pragma unroll
                for (int r=0;r<4;r++){
                    int prow = quad*4 + r;
                    float p = exp2f(s[j][r]*SC);
                    if (kt == bqt){
                        int row = q0b + wave*16 + prow;
                        int col = kt*64 + j*16 + l15;
                        if (col > row) p = 0.f;
                    }
                    lpB[r] += p;
                    int ch = (2*j + (l15>>3)) ^ (prow&7);
                    pl[prow*64 + ch*8 + (l15&7)] = f2bf(p);
                }
            short8 pf0 = *(const short8*)&pl[l15*64 + ((quad     ^ (l15&7)))*8];
            short8 pf1 = *(const short8*)&pl[l15*64 + (((quad+4) ^ (l15&7)))*8];
#pragma unroll
            for (int n=0;n<4;n++){
                accB[n] = __builtin_amdgcn_mfma_f32_16x16x32_bf16(pf0, vf0[n], accB[n], 0, 0, 0);
                accB[n] = __builtin_amdgcn_mfma_f32_16x16x32_bf16(pf1, vf1[n], accB[n], 0, 0, 0);
            }
        }

        // ---- phase A (Q-tile aqt): active while kt <= aqt ----
        if (kt <= aqt){
            floatx4 s[4];
#pragma unroll
            for (int j=0;j<4;j++){
                floatx4 zz = (floatx4){0.f,0.f,0.f,0.f};
                zz = __builtin_amdgcn_mfma_f32_16x16x32_bf16(qa0, kf0[j], zz, 0, 0, 0);
                zz = __builtin_amdgcn_mfma_f32_16x16x32_bf16(qa1, kf1[j], zz, 0, 0, 0);
                s[j] = zz;
            }
#pragma unroll
            for (int j=0;j<4;j++)
#pragma unroll
                for (int r=0;r<4;r++){
                    int prow = quad*4 + r;
                    float p = exp2f(s[j][r]*SC);
                    if (kt == aqt){
                        int row = q0a + wave*16 + prow;
                        int col = kt*64 + j*16 + l15;
                        if (col > row) p = 0.f;
                    }
                    lpA[r] += p;
                    int ch = (2*j + (l15>>3)) ^ (prow&7);
                    pl[prow*64 + ch*8 + (l15&7)] = f2bf(p);
                }
            short8 pf0 = *(const short8*)&pl[l15*64 + ((quad     ^ (l15&7)))*8];
            short8 pf1 = *(const short8*)&pl[l15*64 + (((quad+4) ^ (l15&7)))*8];
#pragma unroll
            for (int n=0;n<4;n++){
                accA[n] = __builtin_amdgcn_mfma_f32_16x16x32_bf16(pf0, vf0[n], accA[n], 0, 0, 0);
                accA[n] = __builtin_amdgcn_mfma_f32_16x16x32_bf16(pf1, vf1[n], accA[n], 0, 0, 0);
            }
        }
        cur ^= 1;
    }

#pragma unroll
    for (int r=0;r<4;r++){
        float va = lpA[r], vb = lpB[r];
        va += __shfl_xor(va, 1); vb += __shfl_xor(vb, 1);
        va += __shfl_xor(va, 2); vb += __shfl_xor(vb, 2);
        va += __shfl_xor(va, 4); vb += __shfl_xor(vb, 4);
        va += __shfl_xor(va, 8); vb += __shfl_xor(vb, 8);
        lpA[r] = va; lpB[r] = vb;
    }
#pragma unroll
    for (int n=0;n<4;n++)
#pragma unroll
        for (int r=0;r<4;r++){
            float oa = accA[n][r] / lpA[r];
            float ob = accB[n][r] / lpB[r];
            ctx[(size_t)(b*SS + q0a + wave*16 + quad*4 + r)*DD + h*HDIM + n*16 + l15] = f2bf(oa);
            ctx[(size_t)(b*SS + q0b + wave*16 + quad*4 + r)*DD + h*HDIM + n*16 + l15] = f2bf(ob);
        }
}

// ---------------- LayerNorm (fp32 in -> bf16 bits out), one block per row ----------------
__global__ __launch_bounds__(256) void ln_kernel(const float* __restrict__ x,
                                                 const float* __restrict__ g,
                                                 const float* __restrict__ bparm,
                                                 unsigned short* __restrict__ out)
{
    __shared__ float red[8];
    const int row = blockIdx.x;
    const int tid = threadIdx.x;
    const float* xr = x + (size_t)row*DD;
    float4 v = *(const float4*)(xr + tid*4);
    float s  = v.x+v.y+v.z+v.w;
    float sq = v.x*v.x + v.y*v.y + v.z*v.z + v.w*v.w;
#pragma unroll
    for (int off=1; off<64; off<<=1){ s += __shfl_xor(s, off); sq += __shfl_xor(sq, off); }
    if ((tid & 63) == 0){ red[tid>>6] = s; red[4 + (tid>>6)] = sq; }
    __syncthreads();
    float ts = red[0]+red[1]+red[2]+red[3];
    float tq = red[4]+red[5]+red[6]+red[7];
    float mean = ts * (1.f/DD);
    float var  = tq * (1.f/DD) - mean*mean;
    float inv  = rsqrtf(var + 1e-5f);
    float4 gv = *(const float4*)(g + tid*4);
    float4 bv = *(const float4*)(bparm + tid*4);
    ushort4 o;
    o.x = f2bf((v.x-mean)*inv*gv.x + bv.x);
    o.y = f2bf((v.y-mean)*inv*gv.y + bv.y);
    o.z = f2bf((v.z-mean)*inv*gv.z + bv.z);
    o.w = f2bf((v.w-mean)*inv*gv.w + bv.w);
    *(ushort4*)(out + (size_t)row*DD + tid*4) = o;
}

// ---------------- transpose + cast: in fp32 [R,C] -> out bf16 [C,R], batched over z ----------------
__global__ __launch_bounds__(256) void castT_kernel(const float* __restrict__ in,
                                                    unsigned short* __restrict__ out,
                                                    int R, int C)
{
    __shared__ float t[32][33];
    const size_t zoff = (size_t)blockIdx.z * R * C;
    in  += zoff; out += zoff;
    const int tr = blockIdx.y*32, tc = blockIdx.x*32;
    const int lr = threadIdx.x >> 5, lc = threadIdx.x & 31;
#pragma unroll
    for (int i=0;i<4;i++)
        t[lr + i*8][lc] = in[(size_t)(tr + lr + i*8)*C + tc + lc];
    __syncthreads();
#pragma unroll
    for (int i=0;i<4;i++)
        out[(size_t)(tc + lr + i*8)*R + tr + lc] = f2bf(t[lc][lr + i*8]);
}

// ---------------- 4 square 1024x1024 transposes in one dispatch (z selects weight) ----
__global__ __launch_bounds__(256) void castT4_kernel(const float* __restrict__ i0,
                                                     const float* __restrict__ i1,
                                                     const float* __restrict__ i2,
                                                     const float* __restrict__ i3,
                                                     unsigned short* __restrict__ o0,
                                                     unsigned short* __restrict__ o1,
                                                     unsigned short* __restrict__ o2,
                                                     unsigned short* __restrict__ o3)
{
    __shared__ float t[32][33];
    const int z = blockIdx.z;
    const float* in = (z==0) ? i0 : (z==1) ? i1 : (z==2) ? i2 : i3;
    unsigned short* out = (z==0) ? o0 : (z==1) ? o1 : (z==2) ? o2 : o3;
    const int tr = blockIdx.y*32, tc = blockIdx.x*32;
    const int lr = threadIdx.x >> 5, lc = threadIdx.x & 31;
#pragma unroll
    for (int i=0;i<4;i++)
        t[lr + i*8][lc] = in[(size_t)(tr + lr + i*8)*1024 + tc + lc];
    __syncthreads();
#pragma unroll
    for (int i=0;i<4;i++)
        out[(size_t)(tc + lr + i*8)*1024 + tr + lc] = f2bf(t[lc][lr + i*8]);
}

extern "C" void kernel_launch(void* const* d_in, const int* in_sizes, int n_in,
                              void* d_out, int out_size, void* d_ws, size_t ws_size,
                              hipStream_t stream)
{
    const float* x     = (const float*)d_in[0];
    // d_in[1] = attention_mask (causal; handled analytically)
    const float* ln1_g = (const float*)d_in[2];
    const float* ln1_b = (const float*)d_in[3];
    const float* Wq    = (const float*)d_in[4];
    const float* Wk    = (const float*)d_in[5];
    const float* Wv    = (const float*)d_in[6];
    const float* Wo    = (const float*)d_in[7];
    const float* ln2_g = (const float*)d_in[8];
    const float* ln2_b = (const float*)d_in[9];
    const float* W1    = (const float*)d_in[10];
    const float* W2    = (const float*)d_in[11];

    float* out  = (float*)d_out;                       // [B,S,D]
    float* kout = out  + (size_t)RR*DD;                // [B,H,S,64]
    float* vout = kout + (size_t)BB*HH*SS*HDIM;        // [B,H,S,64]

    char* w = (char*)d_ws;
    auto alloc = [&](size_t bytes) -> char* {
        char* p = w; w += (bytes + 255) & ~(size_t)255; return p;
    };
    unsigned short* qkvT  = (unsigned short*)alloc((size_t)3072*1024*2); // [3072,1024]
    unsigned short* WoT   = (unsigned short*)alloc((size_t)1024*1024*2); // [1024,1024]
    unsigned short* W1T   = (unsigned short*)alloc((size_t)4096*1024*2); // [4096,1024]
    unsigned short* W2T   = (unsigned short*)alloc((size_t)1024*4096*2); // [1024,4096]
    unsigned short* h_bf  = (unsigned short*)alloc((size_t)RR*DD*2);     // LN output (reused)
    unsigned short* q_bf  = (unsigned short*)alloc((size_t)RR*DD*2);
    unsigned short* k_bf  = (unsigned short*)alloc((size_t)RR*DD*2);     // [B,H,S,64]
    unsigned short* vt_bf = (unsigned short*)alloc((size_t)RR*DD*2);     // [B,H,64,S]
    unsigned short* ctx_bf= (unsigned short*)alloc((size_t)RR*DD*2);
    unsigned short* act_bf= (unsigned short*)alloc((size_t)RR*FF*2);
    float* x1     = (float*)alloc((size_t)RR*DD*4);
    float* fpart  = (float*)alloc((size_t)2*RR*DD*4);  // FFN2 split-K partials (2 x 16 MB)

    // --- weight transposes (fp32 -> bf16 [N,K]) ---
    castT4_kernel<<<dim3(32,32,4), 256, 0, stream>>>(
        Wq, Wk, Wv, Wo, qkvT, qkvT + 1024*1024, qkvT + 2*1024*1024, WoT);
    castT_kernel<<<dim3(128,32,1), 256, 0, stream>>>(W1, W1T, 1024, 4096);
    castT_kernel<<<dim3(32,128,1), 256, 0, stream>>>(W2, W2T, 4096, 1024);

    // --- attention sublayer ---
    ln_kernel<<<RR, 256, 0, stream>>>(x, ln1_g, ln1_b, h_bf);
    // QKV GEMM (BM=128 measured-best) with fused split-scatter epilogue
    gemm_bt<128,128,1><<<dim3(3072/128, RR/128), 256, 0, stream>>>(
        h_bf, qkvT, RR, 3072, 1024, 1024, nullptr, nullptr, nullptr, q_bf, kout, k_bf, vout);
    // v fp32 [B,H,S,64] -> vt bf16 [B,H,64,S]
    castT_kernel<<<dim3(2, 64, BB*HH), 256, 0, stream>>>(vout, vt_bf, SS, HDIM);
    // paired-Q flash attention (frozen R0 body)
    attn_kernel<<<dim3(16, BB*HH), 256, 0, stream>>>(q_bf, k_bf, vt_bf, ctx_bf);
    // Wo GEMM + residual (BM=128/BN=64 single-buffer, measured-best)
    gemm_bt<128,64,2><<<dim3(1024/64, RR/128), 256, 0, stream>>>(
        ctx_bf, WoT, RR, 1024, 1024, 1024, x1, x, nullptr, nullptr, nullptr, nullptr, nullptr);

    // --- FFN sublayer ---
    ln_kernel<<<RR, 256, 0, stream>>>(x1, ln2_g, ln2_b, h_bf);
    // FFN1 GEMM: R11 experiment — 256x256-tile 8-wave counted-vmcnt pipeline + GELU
    gemm256_gelu<<<dim3(4096/256, RR/256), 512, 0, stream>>>(
        h_bf, W1T, 1024, 4096, act_bf);
    // FFN2 GEMM: split-K2, BM=128/BN=128 (measured-best) + combine
    gemm_bt<128,128,4><<<dim3(1024/128, RR/128, 2), 256, 0, stream>>>(
        act_bf, W2T, RR, 1024, 4096, 2048, fpart, nullptr, nullptr, nullptr, nullptr, nullptr, nullptr);
    combine2_kernel<<<(RR*DD/4 + 255)/256, 256, 0, stream>>>(
        fpart, fpart + (size_t)RR*DD, x1, out, RR*DD/4);
}

// Round 12
// 353.755 us; speedup vs baseline: 1.0926x; 1.0926x over previous
//
#include <hip/hip_runtime.h>
#include <hip/hip_bf16.h>
#include <cstdint>
#include <cstddef>

#define BB 2
#define SS 2048
#define DD 1024
#define HH 16
#define HDIM 64
#define FF 4096
#define RR (BB*SS)   // 4096 rows total

typedef __attribute__((ext_vector_type(8))) short short8;
typedef __attribute__((ext_vector_type(4))) float floatx4;

__device__ __forceinline__ unsigned short f2bf(float f){
    __hip_bfloat16 h = __float2bfloat16(f);
    return *reinterpret_cast<unsigned short*>(&h);
}

__device__ __forceinline__ void load_lds16(const void* g, void* l){
    __builtin_amdgcn_global_load_lds((__attribute__((address_space(1))) void*)g,
                                     (__attribute__((address_space(3))) void*)l, 16, 0, 0);
}

// LDS tile layout (64-wide bf16 rows): element chunk c (8 elems) of row r lives at
// chunk (c ^ (r&7)). Staging swizzles the global SOURCE column; readers XOR the
// chunk index with (row&7). Measured: SQ_LDS_BANK_CONFLICT == 0 with this.

// ---------------- GEMM: C[M,N] = A[M,K] * B[N,K]^T (bf16 in) ----------------
// FINAL CONFIG (= R10, measured-best 358.2us total). Session ledger:
//   single-buffer (256,3):        BEST (R6 -11us vs dbuf; R10 358.2)
//   dbuf-2 prefetch:              worse (R0-R5)
//   3-buf counted-vmcnt @128:     neutral (R5)
//   BM=256 @ 2-barrier:           -5us (R8)
//   min-waves pin 4/5:            -7us (R9)
//   256^2 8-wave counted-vmcnt:   -28us (R11: 1 block/CU lockstep, MfmaUtil 13.8%,
//                                 nothing busy — deep pipeline needs the full
//                                 fine-interleaved 8-phase template, not a graft)
// Mechanism: stage -> barrier -> compute -> barrier; cross-block overlap (m114) at
// 3+ blocks/CU supplies the pipelining.
// XCD-chunked blockIdx swizzle (T1); K-rotation de-convoys co-resident blocks.
// EPI: 1 = QKV split-scatter, 2 = +residual -> fp32, 3 = GELU(sigmoid) -> bf16,
//      4 = fp32 partial store to cf + z*M*N
template<int BM, int BN, int EPI>
__global__ __launch_bounds__(256, 3)
void gemm_bt(const unsigned short* __restrict__ A,
             const unsigned short* __restrict__ B,
             int M, int N, int K, int KS,
             float* __restrict__ cf,
             const float* __restrict__ resid,
             unsigned short* __restrict__ cbf,
             unsigned short* __restrict__ qb,
             float* __restrict__ kout,
             unsigned short* __restrict__ kbf,
             float* __restrict__ vout)
{
    constexpr int MI_M = (BN==128) ? (BM/32) : (BM/64);   // per-wave 16-row tiles
    __shared__ __align__(16) unsigned short As[BM*64];
    __shared__ __align__(16) unsigned short Bs[BN*64];
    const int tid  = threadIdx.x;
    const int lane = tid & 63;
    const int wave = tid >> 6;
    const int quad = lane >> 4, l15 = lane & 15;
    const int wrow = (BN==128) ? (wave>>1)*(BM/2) : wave*(BM/4);
    const int wcol = (BN==128) ? (wave&1)*64 : 0;

    // T1 XCD swizzle: bid%8 = this block's XCD; give each XCD a contiguous run.
    const unsigned gx = gridDim.x;
    const unsigned nwg = gx * gridDim.y;
    const unsigned bid = blockIdx.y * gx + blockIdx.x;
    const unsigned cpx = nwg >> 3;
    const unsigned swz = (bid & 7) * cpx + (bid >> 3);
    const int bx = (int)(swz % gx), by = (int)(swz / gx);

    const int gm0 = by * BM, gn0 = bx * BN;
    const int k0 = blockIdx.z * KS;
    const int niter = KS >> 6;
    const int phase = (int)((unsigned)(bx + by) % (unsigned)niter);

    floatx4 acc[MI_M][4];
#pragma unroll
    for (int i=0;i<MI_M;i++)
#pragma unroll
        for (int j=0;j<4;j++) acc[i][j] = (floatx4){0.f,0.f,0.f,0.f};

    const int rsub = lane >> 3;                    // row within 8-row chunk (= row&7)
    const int d8   = (lane & 7) * 8;               // LDS dest offset within row
    const int ksub = ((lane & 7) ^ rsub) * 8;      // swizzled global source k-offset
    constexpr int nchw = (BM + BN) / 32;           // staging chunks per wave

    auto stage = [&](int kt){
#pragma unroll
        for (int i=0;i<nchw;i++){
            int c = wave*nchw + i;   // wave-uniform chunk id
            if (c < BM/8)
                load_lds16(A + (size_t)(gm0 + c*8 + rsub)*K + kt + ksub,
                           &As[c*512 + rsub*64 + d8]);
            else
                load_lds16(B + (size_t)(gn0 + (c-BM/8)*8 + rsub)*K + kt + ksub,
                           &Bs[(c-BM/8)*512 + rsub*64 + d8]);
        }
    };

    auto compute = [&](){
#pragma unroll
        for (int kk=0; kk<64; kk+=32){
            const int cb4 = kk >> 3;   // 0 or 4
            short8 af[MI_M], bfr[4];
#pragma unroll
            for (int mi=0;mi<MI_M;mi++){
                int row = wrow + mi*16 + l15;
                af[mi] = *(const short8*)&As[row*64 + (((cb4+quad) ^ (row&7)))*8];
            }
#pragma unroll
            for (int ni=0;ni<4;ni++){
                int row = wcol + ni*16 + l15;
                bfr[ni] = *(const short8*)&Bs[row*64 + (((cb4+quad) ^ (row&7)))*8];
            }
#pragma unroll
            for (int mi=0;mi<MI_M;mi++)
#pragma unroll
                for (int ni=0;ni<4;ni++)
                    acc[mi][ni] = __builtin_amdgcn_mfma_f32_16x16x32_bf16(af[mi], bfr[ni], acc[mi][ni], 0, 0, 0);
        }
    };

    for (int it=0; it<niter; it++){
        int j = it + phase; if (j >= niter) j -= niter;
        stage(k0 + j*64);
        __syncthreads();   // vmcnt(0)+lgkmcnt(0) drain: tile present for all waves
        compute();
        __syncthreads();   // all waves' ds_reads done before next stage overwrites
    }

#pragma unroll
    for (int mi=0;mi<MI_M;mi++)
#pragma unroll
        for (int ni=0;ni<4;ni++)
#pragma unroll
            for (int r=0;r<4;r++){
                int row = gm0 + wrow + mi*16 + quad*4 + r;
                int col = gn0 + wcol + ni*16 + l15;
                float v = acc[mi][ni][r];
                if constexpr (EPI == 1){
                    // QKV split: region is tile-uniform (gn0 aligned to 128 < 1024)
                    int region = gn0 >> 10;
                    if (region == 0){
                        qb[(size_t)row*1024 + col] = f2bf(v);
                    } else {
                        int c1 = col & 1023;
                        int h = c1 >> 6, d = c1 & 63;
                        int b = row >> 11, s = row & (SS-1);
                        size_t o = ((size_t)((b*HH + h)*SS + s))*HDIM + d;
                        if (region == 1){ kout[o] = v; kbf[o] = f2bf(v); }
                        else            { vout[o] = v; }
                    }
                } else if constexpr (EPI == 2){
                    size_t o = (size_t)row*N + col;
                    cf[o] = v + resid[o];
                } else if constexpr (EPI == 3){
                    // tanh-GELU via sigmoid identity: 0.5(1+tanh(u)) = 1/(1+e^-2u)
                    float u = v*(0.79788456f + 0.0356774081f*v*v);
                    float g = v / (1.f + exp2f(-2.88539008f*u));
                    cbf[(size_t)row*N + col] = f2bf(g);
                } else {   // EPI == 4: split-K fp32 partial
                    cf[(size_t)blockIdx.z*M*N + (size_t)row*N + col] = v;
                }
            }
}

// ---------------- split-K combine: out = p0 + p1 + resid (float4) ----------------
__global__ __launch_bounds__(256) void combine2_kernel(const float* __restrict__ p0,
                                                       const float* __restrict__ p1,
                                                       const float* __restrict__ resid,
                                                       float* __restrict__ out, int n4)
{
    const int i = blockIdx.x*256 + threadIdx.x;
    if (i >= n4) return;
    float4 a = ((const float4*)p0)[i];
    float4 b = ((const float4*)p1)[i];
    float4 c = ((const float4*)resid)[i];
    ((float4*)out)[i] = make_float4(a.x+b.x+c.x, a.y+b.y+c.y, a.z+b.z+c.z, a.w+b.w+c.w);
}

// ---------------- flash attention: paired causal Q-tiles — FROZEN R0 body ----------
// Variant ledger: paired-R0 56.4 | setprio 59.0 | split-loop 60.0 | split-KV 62.9 |
// single-Q 75.6. Every restructure lost; do not modify.
__global__ __launch_bounds__(256) void attn_kernel(const unsigned short* __restrict__ qbf,
                                                   const unsigned short* __restrict__ kbf,
                                                   const unsigned short* __restrict__ vtbf,
                                                   unsigned short* __restrict__ ctx)
{
    __shared__ unsigned short Ks[2][64*64];   // 16 KB
    __shared__ unsigned short Vs[2][64*64];   // 16 KB
    __shared__ unsigned short Ps[4][16*64];   //  8 KB (per-wave P buffers)
    const int tid  = threadIdx.x;
    const int lane = tid & 63;
    const int wave = tid >> 6;
    const int quad = lane >> 4, l15 = lane & 15;
    const int aqt = blockIdx.x;            // 0..15
    const int bqt = 31 - aqt;              // 16..31
    const int bh = blockIdx.y;
    const int b = bh >> 4, h = bh & 15;
    const int q0a = aqt * 64, q0b = bqt * 64;

    const unsigned short* kb  = kbf  + (size_t)bh * SS * HDIM;
    const unsigned short* vtb = vtbf + (size_t)bh * HDIM * SS;

    const unsigned short* qra = qbf + (size_t)(b*SS + q0a + wave*16 + l15)*DD + h*HDIM + quad*8;
    const unsigned short* qrb = qbf + (size_t)(b*SS + q0b + wave*16 + l15)*DD + h*HDIM + quad*8;
    short8 qa0 = *(const short8*)qra;
    short8 qa1 = *(const short8*)(qra + 32);
    short8 qb0 = *(const short8*)qrb;
    short8 qb1 = *(const short8*)(qrb + 32);

    float lpA[4] = {0.f,0.f,0.f,0.f}, lpB[4] = {0.f,0.f,0.f,0.f};
    floatx4 accA[4], accB[4];
#pragma unroll
    for (int n=0;n<4;n++){ accA[n] = (floatx4){0.f,0.f,0.f,0.f}; accB[n] = (floatx4){0.f,0.f,0.f,0.f}; }

    const int r8 = lane >> 3;                    // staged row mod 8
    const int c8 = ((lane & 7) ^ r8) * 8;        // swizzled source offset
    const int d8 = (lane & 7) * 8;               // dest offset within row
    const int nkt = bqt + 1;
    const float SC = 0.125f * 1.44269504f;       // 1/sqrt(64) * log2(e)

#pragma unroll
    for (int p=0;p<2;p++){
        int row = p*32 + wave*8 + r8;
        load_lds16(kb  + (size_t)row*HDIM + c8,  &Ks[0][row*64 + d8]);
        load_lds16(vtb + (size_t)row*SS   + c8,  &Vs[0][row*64 + d8]);
    }

    unsigned short* pl = Ps[wave];
    int cur = 0;
    for (int kt=0; kt<nkt; kt++){
        __syncthreads();
        if (kt+1 < nkt){
            int nb = cur ^ 1;
#pragma unroll
            for (int p=0;p<2;p++){
                int row = p*32 + wave*8 + r8;
                load_lds16(kb  + (size_t)((kt+1)*64 + row)*HDIM + c8, &Ks[nb][row*64 + d8]);
                load_lds16(vtb + (size_t)row*SS + (size_t)(kt+1)*64 + c8, &Vs[nb][row*64 + d8]);
            }
        }
        const unsigned short* ks = Ks[cur];
        const unsigned short* vs = Vs[cur];

        short8 kf0[4], kf1[4];
#pragma unroll
        for (int j=0;j<4;j++){
            int row = j*16 + l15;
            kf0[j] = *(const short8*)&ks[row*64 + ((quad     ^ (row&7)))*8];
            kf1[j] = *(const short8*)&ks[row*64 + (((quad+4) ^ (row&7)))*8];
        }
        short8 vf0[4], vf1[4];
#pragma unroll
        for (int n=0;n<4;n++){
            int row = n*16 + l15;
            vf0[n] = *(const short8*)&vs[row*64 + ((quad     ^ (row&7)))*8];
            vf1[n] = *(const short8*)&vs[row*64 + (((quad+4) ^ (row&7)))*8];
        }

        // ---- phase B (Q-tile bqt): always active ----
        {
            floatx4 s[4];
#pragma unroll
            for (int j=0;j<4;j++){
                floatx4 zz = (floatx4){0.f,0.f,0.f,0.f};
                zz = __builtin_amdgcn_mfma_f32_16x16x32_bf16(qb0, kf0[j], zz, 0, 0, 0);
                zz = __builtin_amdgcn_mfma_f32_16x16x32_bf16(qb1, kf1[j], zz, 0, 0, 0);
                s[j] = zz;
            }
#pragma unroll
            for (int j=0;j<4;j++)
#pragma unroll
                for (int r=0;r<4;r++){
                    int prow = quad*4 + r;
                    float p = exp2f(s[j][r]*SC);
                    if (kt == bqt){
                        int row = q0b + wave*16 + prow;
                        int col = kt*64 + j*16 + l15;
                        if (col > row) p = 0.f;
                    }
                    lpB[r] += p;
                    int ch = (2*j + (l15>>3)) ^ (prow&7);
                    pl[prow*64 + ch*8 + (l15&7)] = f2bf(p);
                }
            short8 pf0 = *(const short8*)&pl[l15*64 + ((quad     ^ (l15&7)))*8];
            short8 pf1 = *(const short8*)&pl[l15*64 + (((quad+4) ^ (l15&7)))*8];
#pragma unroll
            for (int n=0;n<4;n++){
                accB[n] = __builtin_amdgcn_mfma_f32_16x16x32_bf16(pf0, vf0[n], accB[n], 0, 0, 0);
                accB[n] = __builtin_amdgcn_mfma_f32_16x16x32_bf16(pf1, vf1[n], accB[n], 0, 0, 0);
            }
        }

        // ---- phase A (Q-tile aqt): active while kt <= aqt ----
        if (kt <= aqt){
            floatx4 s[4];
#pragma unroll
            for (int j=0;j<4;j++){
                floatx4 zz = (floatx4){0.f,0.f,0.f,0.f};
                zz = __builtin_amdgcn_mfma_f32_16x16x32_bf16(qa0, kf0[j], zz, 0, 0, 0);
                zz = __builtin_amdgcn_mfma_f32_16x16x32_bf16(qa1, kf1[j], zz, 0, 0, 0);
                s[j] = zz;
            }
#pragma unroll
            for (int j=0;j<4;j++)
#pragma unroll
                for (int r=0;r<4;r++){
                    int prow = quad*4 + r;
                    float p = exp2f(s[j][r]*SC);
                    if (kt == aqt){
                        int row = q0a + wave*16 + prow;
                        int col = kt*64 + j*16 + l15;
                        if (col > row) p = 0.f;
                    }
                    lpA[r] += p;
                    int ch = (2*j + (l15>>3)) ^ (prow&7);
                    pl[prow*64 + ch*8 + (l15&7)] = f2bf(p);
                }
            short8 pf0 = *(const short8*)&pl[l15*64 + ((quad     ^ (l15&7)))*8];
            short8 pf1 = *(const short8*)&pl[l15*64 + (((quad+4) ^ (l15&7)))*8];
#pragma unroll
            for (int n=0;n<4;n++){
                accA[n] = __builtin_amdgcn_mfma_f32_16x16x32_bf16(pf0, vf0[n], accA[n], 0, 0, 0);
                accA[n] = __builtin_amdgcn_mfma_f32_16x16x32_bf16(pf1, vf1[n], accA[n], 0, 0, 0);
            }
        }
        cur ^= 1;
    }

#pragma unroll
    for (int r=0;r<4;r++){
        float va = lpA[r], vb = lpB[r];
        va += __shfl_xor(va, 1); vb += __shfl_xor(vb, 1);
        va += __shfl_xor(va, 2); vb += __shfl_xor(vb, 2);
        va += __shfl_xor(va, 4); vb += __shfl_xor(vb, 4);
        va += __shfl_xor(va, 8); vb += __shfl_xor(vb, 8);
        lpA[r] = va; lpB[r] = vb;
    }
#pragma unroll
    for (int n=0;n<4;n++)
#pragma unroll
        for (int r=0;r<4;r++){
            float oa = accA[n][r] / lpA[r];
            float ob = accB[n][r] / lpB[r];
            ctx[(size_t)(b*SS + q0a + wave*16 + quad*4 + r)*DD + h*HDIM + n*16 + l15] = f2bf(oa);
            ctx[(size_t)(b*SS + q0b + wave*16 + quad*4 + r)*DD + h*HDIM + n*16 + l15] = f2bf(ob);
        }
}

// ---------------- LayerNorm (fp32 in -> bf16 bits out), one block per row ----------------
__global__ __launch_bounds__(256) void ln_kernel(const float* __restrict__ x,
                                                 const float* __restrict__ g,
                                                 const float* __restrict__ bparm,
                                                 unsigned short* __restrict__ out)
{
    __shared__ float red[8];
    const int row = blockIdx.x;
    const int tid = threadIdx.x;
    const float* xr = x + (size_t)row*DD;
    float4 v = *(const float4*)(xr + tid*4);
    float s  = v.x+v.y+v.z+v.w;
    float sq = v.x*v.x + v.y*v.y + v.z*v.z + v.w*v.w;
#pragma unroll
    for (int off=1; off<64; off<<=1){ s += __shfl_xor(s, off); sq += __shfl_xor(sq, off); }
    if ((tid & 63) == 0){ red[tid>>6] = s; red[4 + (tid>>6)] = sq; }
    __syncthreads();
    float ts = red[0]+red[1]+red[2]+red[3];
    float tq = red[4]+red[5]+red[6]+red[7];
    float mean = ts * (1.f/DD);
    float var  = tq * (1.f/DD) - mean*mean;
    float inv  = rsqrtf(var + 1e-5f);
    float4 gv = *(const float4*)(g + tid*4);
    float4 bv = *(const float4*)(bparm + tid*4);
    ushort4 o;
    o.x = f2bf((v.x-mean)*inv*gv.x + bv.x);
    o.y = f2bf((v.y-mean)*inv*gv.y + bv.y);
    o.z = f2bf((v.z-mean)*inv*gv.z + bv.z);
    o.w = f2bf((v.w-mean)*inv*gv.w + bv.w);
    *(ushort4*)(out + (size_t)row*DD + tid*4) = o;
}

// ---------------- transpose + cast: in fp32 [R,C] -> out bf16 [C,R], batched over z ----------------
__global__ __launch_bounds__(256) void castT_kernel(const float* __restrict__ in,
                                                    unsigned short* __restrict__ out,
                                                    int R, int C)
{
    __shared__ float t[32][33];
    const size_t zoff = (size_t)blockIdx.z * R * C;
    in  += zoff; out += zoff;
    const int tr = blockIdx.y*32, tc = blockIdx.x*32;
    const int lr = threadIdx.x >> 5, lc = threadIdx.x & 31;
#pragma unroll
    for (int i=0;i<4;i++)
        t[lr + i*8][lc] = in[(size_t)(tr + lr + i*8)*C + tc + lc];
    __syncthreads();
#pragma unroll
    for (int i=0;i<4;i++)
        out[(size_t)(tc + lr + i*8)*R + tr + lc] = f2bf(t[lc][lr + i*8]);
}

// ---------------- R12: ALL weight transposes in ONE dispatch (1D grid, id-decoded) --
// Replaces castT4 + castT(W1) + castT(W2): same proven 32x32 tile body, pure index
// relabeling. id < 4096: four 1024x1024 squares (1024 tiles each); id < 8192: W1
// (1024x4096); else W2 (4096x1024). Saves 2 dispatch boundaries + tail overlap.
__global__ __launch_bounds__(256) void castT_all(const float* __restrict__ Wq,
                                                 const float* __restrict__ Wk,
                                                 const float* __restrict__ Wv,
                                                 const float* __restrict__ Wo,
                                                 const float* __restrict__ W1,
                                                 const float* __restrict__ W2,
                                                 unsigned short* __restrict__ qT,
                                                 unsigned short* __restrict__ kT,
                                                 unsigned short* __restrict__ vT,
                                                 unsigned short* __restrict__ oT,
                                                 unsigned short* __restrict__ w1T,
                                                 unsigned short* __restrict__ w2T)
{
    __shared__ float t[32][33];
    const int id = blockIdx.x;
    const float* in; unsigned short* out; int R, C, tile;
    if (id < 4096){
        int z = id >> 10; tile = id & 1023; R = 1024; C = 1024;
        in  = (z==0) ? Wq : (z==1) ? Wk : (z==2) ? Wv : Wo;
        out = (z==0) ? qT : (z==1) ? kT : (z==2) ? vT : oT;
    } else if (id < 8192){
        tile = id - 4096; in = W1; out = w1T; R = 1024; C = 4096;
    } else {
        tile = id - 8192; in = W2; out = w2T; R = 4096; C = 1024;
    }
    const int tilesX = C >> 5;
    const int tr = (tile / tilesX) * 32, tc = (tile % tilesX) * 32;
    const int lr = threadIdx.x >> 5, lc = threadIdx.x & 31;
#pragma unroll
    for (int i=0;i<4;i++)
        t[lr + i*8][lc] = in[(size_t)(tr + lr + i*8)*C + tc + lc];
    __syncthreads();
#pragma unroll
    for (int i=0;i<4;i++)
        out[(size_t)(tc + lr + i*8)*R + tr + lc] = f2bf(t[lc][lr + i*8]);
}

extern "C" void kernel_launch(void* const* d_in, const int* in_sizes, int n_in,
                              void* d_out, int out_size, void* d_ws, size_t ws_size,
                              hipStream_t stream)
{
    const float* x     = (const float*)d_in[0];
    // d_in[1] = attention_mask (causal; handled analytically)
    const float* ln1_g = (const float*)d_in[2];
    const float* ln1_b = (const float*)d_in[3];
    const float* Wq    = (const float*)d_in[4];
    const float* Wk    = (const float*)d_in[5];
    const float* Wv    = (const float*)d_in[6];
    const float* Wo    = (const float*)d_in[7];
    const float* ln2_g = (const float*)d_in[8];
    const float* ln2_b = (const float*)d_in[9];
    const float* W1    = (const float*)d_in[10];
    const float* W2    = (const float*)d_in[11];

    float* out  = (float*)d_out;                       // [B,S,D]
    float* kout = out  + (size_t)RR*DD;                // [B,H,S,64]
    float* vout = kout + (size_t)BB*HH*SS*HDIM;        // [B,H,S,64]

    char* w = (char*)d_ws;
    auto alloc = [&](size_t bytes) -> char* {
        char* p = w; w += (bytes + 255) & ~(size_t)255; return p;
    };
    unsigned short* qkvT  = (unsigned short*)alloc((size_t)3072*1024*2); // [3072,1024]
    unsigned short* WoT   = (unsigned short*)alloc((size_t)1024*1024*2); // [1024,1024]
    unsigned short* W1T   = (unsigned short*)alloc((size_t)4096*1024*2); // [4096,1024]
    unsigned short* W2T   = (unsigned short*)alloc((size_t)1024*4096*2); // [1024,4096]
    unsigned short* h_bf  = (unsigned short*)alloc((size_t)RR*DD*2);     // LN output (reused)
    unsigned short* q_bf  = (unsigned short*)alloc((size_t)RR*DD*2);
    unsigned short* k_bf  = (unsigned short*)alloc((size_t)RR*DD*2);     // [B,H,S,64]
    unsigned short* vt_bf = (unsigned short*)alloc((size_t)RR*DD*2);     // [B,H,64,S]
    unsigned short* ctx_bf= (unsigned short*)alloc((size_t)RR*DD*2);
    unsigned short* act_bf= (unsigned short*)alloc((size_t)RR*FF*2);
    float* x1     = (float*)alloc((size_t)RR*DD*4);
    float* fpart  = (float*)alloc((size_t)2*RR*DD*4);  // FFN2 split-K partials (2 x 16 MB)

    // --- ALL weight transposes (fp32 -> bf16 [N,K]) in one dispatch ---
    castT_all<<<12288, 256, 0, stream>>>(
        Wq, Wk, Wv, Wo, W1, W2,
        qkvT, qkvT + 1024*1024, qkvT + 2*1024*1024, WoT, W1T, W2T);

    // --- attention sublayer ---
    ln_kernel<<<RR, 256, 0, stream>>>(x, ln1_g, ln1_b, h_bf);
    // QKV GEMM (BM=128 measured-best) with fused split-scatter epilogue
    gemm_bt<128,128,1><<<dim3(3072/128, RR/128), 256, 0, stream>>>(
        h_bf, qkvT, RR, 3072, 1024, 1024, nullptr, nullptr, nullptr, q_bf, kout, k_bf, vout);
    // v fp32 [B,H,S,64] -> vt bf16 [B,H,64,S]
    castT_kernel<<<dim3(2, 64, BB*HH), 256, 0, stream>>>(vout, vt_bf, SS, HDIM);
    // paired-Q flash attention (frozen R0 body)
    attn_kernel<<<dim3(16, BB*HH), 256, 0, stream>>>(q_bf, k_bf, vt_bf, ctx_bf);
    // Wo GEMM + residual (BM=128/BN=64 single-buffer, measured-best)
    gemm_bt<128,64,2><<<dim3(1024/64, RR/128), 256, 0, stream>>>(
        ctx_bf, WoT, RR, 1024, 1024, 1024, x1, x, nullptr, nullptr, nullptr, nullptr, nullptr);

    // --- FFN sublayer ---
    ln_kernel<<<RR, 256, 0, stream>>>(x1, ln2_g, ln2_b, h_bf);
    // FFN1 GEMM (BM=128 measured-best, reverted from R11's 256^2 pipeline) + GELU
    gemm_bt<128,128,3><<<dim3(4096/128, RR/128), 256, 0, stream>>>(
        h_bf, W1T, RR, 4096, 1024, 1024, nullptr, nullptr, act_bf, nullptr, nullptr, nullptr, nullptr);
    // FFN2 GEMM: split-K2, BM=128/BN=128 (measured-best) + combine
    gemm_bt<128,128,4><<<dim3(1024/128, RR/128, 2), 256, 0, stream>>>(
        act_bf, W2T, RR, 1024, 4096, 2048, fpart, nullptr, nullptr, nullptr, nullptr, nullptr, nullptr);
    combine2_kernel<<<(RR*DD/4 + 255)/256, 256, 0, stream>>>(
        fpart, fpart + (size_t)RR*DD, x1, out, RR*DD/4);
}